// Round 7
// baseline (1793.338 us; speedup 1.0000x reference)
//
#include <hip/hip_runtime.h>
#include <hip/hip_bf16.h>

#define D 48
#define GNUM 64
#define HDIM 128
#define ODIM 12
#define BN_EPS 1e-5f

typedef _Float16 half2v __attribute__((ext_vector_type(2)));
typedef _Float16 half4v __attribute__((ext_vector_type(4)));
typedef _Float16 half8v __attribute__((ext_vector_type(8)));

#if __has_builtin(__builtin_amdgcn_fdot2)
#define FDOT2(a, b, c) __builtin_amdgcn_fdot2((a), (b), (c), false)
#else
#define FDOT2(a, b, c) ((c) + (float)(a)[0] * (float)(b)[0] + (float)(a)[1] * (float)(b)[1])
#endif

// ---------------- setup kernels ----------------

__global__ __launch_bounds__(256) void k_deg(const int* __restrict__ row, int* __restrict__ deg, int E) {
    int e = blockIdx.x * 256 + threadIdx.x;
    if (e < E) atomicAdd(&deg[row[e]], 1);
}

__global__ __launch_bounds__(256) void k_scan1(const int* __restrict__ deg, int* __restrict__ incl,
                                               int* __restrict__ bsum, int N) {
    __shared__ int s[256];
    int i = blockIdx.x * 256 + threadIdx.x;
    s[threadIdx.x] = (i < N) ? deg[i] : 0;
    __syncthreads();
    for (int off = 1; off < 256; off <<= 1) {
        int t = (threadIdx.x >= off) ? s[threadIdx.x - off] : 0;
        __syncthreads();
        s[threadIdx.x] += t;
        __syncthreads();
    }
    if (i < N) incl[i] = s[threadIdx.x];
    if (threadIdx.x == 255) bsum[blockIdx.x] = s[255];
}

__global__ __launch_bounds__(512) void k_scan2(int* __restrict__ bsum, int nb) {
    __shared__ int s[512];
    int t = threadIdx.x;
    s[t] = (t < nb) ? bsum[t] : 0;
    __syncthreads();
    for (int off = 1; off < 512; off <<= 1) {
        int v = (t >= off) ? s[t - off] : 0;
        __syncthreads();
        s[t] += v;
        __syncthreads();
    }
    if (t < nb) bsum[t] = s[t];
}

__global__ __launch_bounds__(256) void k_scan3(const int* __restrict__ incl, const int* __restrict__ bsum,
                                               int* __restrict__ rowptr, int N) {
    int i = blockIdx.x * 256 + threadIdx.x;
    if (i < N) {
        int add = (blockIdx.x > 0) ? bsum[blockIdx.x - 1] : 0;
        rowptr[i + 1] = incl[i] + add;
    }
    if (i == 0) rowptr[0] = 0;
}

// CSR fill, two-phase for write locality.
// Phase A: bin edges into buckets of 256 consecutive rows (bucket = r>>8).
__global__ __launch_bounds__(256) void k_bucket(const int* __restrict__ row, const int* __restrict__ col,
                                                int* __restrict__ btail, int2* __restrict__ bstore,
                                                int E, int CAP) {
    int e = blockIdx.x * 256 + threadIdx.x;
    if (e < E) {
        int r = row[e], c = col[e];
        int b = r >> 8;
        int t = atomicAdd(&btail[b], 1);
        if (t < CAP) bstore[(size_t)b * CAP + t] = make_int2(r, c);
    }
}

// Phase B: one block per bucket; LDS fill counters; scatter confined to a ~16KB ecol window.
__global__ __launch_bounds__(256) void k_fill2(const int2* __restrict__ bstore, const int* __restrict__ btail,
                                               const int* __restrict__ rowptr, int* __restrict__ ecol, int CAP) {
    __shared__ int cnt[256];
    int b = blockIdx.x;
    cnt[threadIdx.x] = 0;
    __syncthreads();
    int tcnt = btail[b];
    if (tcnt > CAP) tcnt = CAP;
    const int2* src = bstore + (size_t)b * CAP;
    for (int t = threadIdx.x; t < tcnt; t += 256) {
        int2 e = src[t];
        int k = atomicAdd(&cnt[e.x & 255], 1);
        ecol[rowptr[e.x] + k] = e.y;
    }
}

// xh = fp16(x); xs = fp16(dinv*x); dinv computed inline from deg and stored.
__global__ __launch_bounds__(256) void k_cvt(const float* __restrict__ x, const int* __restrict__ deg,
                                             _Float16* __restrict__ xh, _Float16* __restrict__ xs,
                                             float* __restrict__ dinv, int n4) {
    int i = blockIdx.x * 256 + threadIdx.x;
    if (i < n4) {
        int node = i / 12;  // D/4 chunks per node
        int dg = deg[node];
        float dv = dg > 0 ? rsqrtf((float)dg) : 0.f;
        if (i % 12 == 0) dinv[node] = dv;
        float4 v = ((const float4*)x)[i];
        half4v h, hs;
        h.x = (_Float16)v.x; h.y = (_Float16)v.y; h.z = (_Float16)v.z; h.w = (_Float16)v.w;
        hs.x = (_Float16)(dv * v.x); hs.y = (_Float16)(dv * v.y);
        hs.z = (_Float16)(dv * v.z); hs.w = (_Float16)(dv * v.w);
        ((half4v*)xh)[i] = h;
        ((half4v*)xs)[i] = hs;
    }
}

// ---------------- gather kernels ----------------
// wave per node; 8 slots x 8 lanes; q<6 active (6 x 16B = 96B row); unroll x2.

// tx1 = -dinv[i] * sum(curs[c]); tx1s = dinv[i] * tx1
__global__ __launch_bounds__(256) void k_lhat(const _Float16* __restrict__ curs, const int* __restrict__ rowptr,
                                              const int* __restrict__ ecol, const float* __restrict__ dinv,
                                              _Float16* __restrict__ tx1, _Float16* __restrict__ tx1s, int N) {
    int lane = threadIdx.x & 63;
    int i = (blockIdx.x * 256 + threadIdx.x) >> 6;
    if (i >= N) return;
    int q = lane & 7, slot = lane >> 3;
    int qc = q < 6 ? q : 5;
    int s = rowptr[i], e = rowptr[i + 1];
    float a[8] = {0.f, 0.f, 0.f, 0.f, 0.f, 0.f, 0.f, 0.f};
    int p = s + slot;
    for (; p + 8 < e; p += 16) {
        int ca = ecol[p], cb = ecol[p + 8];
        half8v ha = *(const half8v*)(curs + (size_t)ca * D + qc * 8);
        half8v hb = *(const half8v*)(curs + (size_t)cb * D + qc * 8);
#pragma unroll
        for (int j = 0; j < 8; ++j) a[j] += (float)ha[j] + (float)hb[j];
    }
    if (p < e) {
        int ca = ecol[p];
        half8v ha = *(const half8v*)(curs + (size_t)ca * D + qc * 8);
#pragma unroll
        for (int j = 0; j < 8; ++j) a[j] += (float)ha[j];
    }
#pragma unroll
    for (int j = 0; j < 8; ++j) {
        a[j] += __shfl_xor(a[j], 8);
        a[j] += __shfl_xor(a[j], 16);
        a[j] += __shfl_xor(a[j], 32);
    }
    if (lane < 6) {
        float di = dinv[i];
        half8v o, os;
#pragma unroll
        for (int j = 0; j < 8; ++j) {
            float t = -di * a[j];
            o[j] = (_Float16)t;
            os[j] = (_Float16)(di * t);
        }
        *(half8v*)(tx1 + (size_t)i * D + lane * 8) = o;
        *(half8v*)(tx1s + (size_t)i * D + lane * 8) = os;
    }
}

// tx2 = -2*dinv[i] * sum(tx1s[c]) - tx0
__global__ __launch_bounds__(256) void k_gather2(const _Float16* __restrict__ tx0, const _Float16* __restrict__ tx1s,
                                                 const int* __restrict__ rowptr, const int* __restrict__ ecol,
                                                 const float* __restrict__ dinv, _Float16* __restrict__ tx2, int N) {
    int lane = threadIdx.x & 63;
    int i = (blockIdx.x * 256 + threadIdx.x) >> 6;
    if (i >= N) return;
    int q = lane & 7, slot = lane >> 3;
    int qc = q < 6 ? q : 5;
    int s = rowptr[i], e = rowptr[i + 1];
    float a[8] = {0.f, 0.f, 0.f, 0.f, 0.f, 0.f, 0.f, 0.f};
    int p = s + slot;
    for (; p + 8 < e; p += 16) {
        int ca = ecol[p], cb = ecol[p + 8];
        half8v ha = *(const half8v*)(tx1s + (size_t)ca * D + qc * 8);
        half8v hb = *(const half8v*)(tx1s + (size_t)cb * D + qc * 8);
#pragma unroll
        for (int j = 0; j < 8; ++j) a[j] += (float)ha[j] + (float)hb[j];
    }
    if (p < e) {
        int ca = ecol[p];
        half8v ha = *(const half8v*)(tx1s + (size_t)ca * D + qc * 8);
#pragma unroll
        for (int j = 0; j < 8; ++j) a[j] += (float)ha[j];
    }
#pragma unroll
    for (int j = 0; j < 8; ++j) {
        a[j] += __shfl_xor(a[j], 8);
        a[j] += __shfl_xor(a[j], 16);
        a[j] += __shfl_xor(a[j], 32);
    }
    if (lane < 6) {
        float sc = -2.f * dinv[i];
        half8v h0 = *(const half8v*)(tx0 + (size_t)i * D + lane * 8);
        half8v o;
#pragma unroll
        for (int j = 0; j < 8; ++j) o[j] = (_Float16)(sc * a[j] - (float)h0[j]);
        *(half8v*)(tx2 + (size_t)i * D + lane * 8) = o;
    }
}

// ---------------- dense: t = relu([tx0|tx1|tx2] @ W + b) ----------------

__global__ __launch_bounds__(256) void k_dense(const _Float16* __restrict__ tx0, const _Float16* __restrict__ tx1,
                                               const _Float16* __restrict__ tx2, const float* __restrict__ W,
                                               const float* __restrict__ b, _Float16* __restrict__ tbuf, int N) {
    __shared__ half2v WH2[72 * D];  // [kp][j] = (W[2kp][j], W[2kp+1][j]); 13824 B
    __shared__ float bL[D];
    for (int t = threadIdx.x; t < 72 * D; t += 256) {
        int kp = t / D, j = t % D;
        half2v w;
        w.x = (_Float16)W[(2 * kp) * D + j];
        w.y = (_Float16)W[(2 * kp + 1) * D + j];
        WH2[t] = w;
    }
    if (threadIdx.x < D) bL[threadIdx.x] = b[threadIdx.x];
    __syncthreads();

    int base = (blockIdx.x * 256 + threadIdx.x) * 2;
    if (base >= N) return;
    bool two = (base + 1) < N;

    const _Float16* rowsA[3] = {tx0 + (size_t)base * D, tx1 + (size_t)base * D, tx2 + (size_t)base * D};
    size_t off2 = two ? D : 0;

    float acc0[D], acc1[D];
#pragma unroll
    for (int j = 0; j < D; ++j) { acc0[j] = bL[j]; acc1[j] = bL[j]; }

    for (int s = 0; s < 3; ++s) {
        const half2v* xa = (const half2v*)rowsA[s];
        const half2v* xb = (const half2v*)(rowsA[s] + off2);
#pragma unroll 4
        for (int g = 0; g < 24; ++g) {
            half2v va = xa[g], vb = xb[g];
            int kp = s * 24 + g;
            const half8v* wr = (const half8v*)&WH2[kp * D];
#pragma unroll
            for (int jc = 0; jc < 12; ++jc) {
                half8v w = wr[jc];
                half2v w0; w0.x = w[0]; w0.y = w[1];
                half2v w1; w1.x = w[2]; w1.y = w[3];
                half2v w2; w2.x = w[4]; w2.y = w[5];
                half2v w3; w3.x = w[6]; w3.y = w[7];
                acc0[jc * 4 + 0] = FDOT2(va, w0, acc0[jc * 4 + 0]);
                acc0[jc * 4 + 1] = FDOT2(va, w1, acc0[jc * 4 + 1]);
                acc0[jc * 4 + 2] = FDOT2(va, w2, acc0[jc * 4 + 2]);
                acc0[jc * 4 + 3] = FDOT2(va, w3, acc0[jc * 4 + 3]);
                acc1[jc * 4 + 0] = FDOT2(vb, w0, acc1[jc * 4 + 0]);
                acc1[jc * 4 + 1] = FDOT2(vb, w1, acc1[jc * 4 + 1]);
                acc1[jc * 4 + 2] = FDOT2(vb, w2, acc1[jc * 4 + 2]);
                acc1[jc * 4 + 3] = FDOT2(vb, w3, acc1[jc * 4 + 3]);
            }
        }
    }

    _Float16* o0 = tbuf + (size_t)base * D;
#pragma unroll
    for (int jc = 0; jc < 12; ++jc) {
        half4v h;
        h.x = (_Float16)fmaxf(acc0[jc * 4 + 0], 0.f);
        h.y = (_Float16)fmaxf(acc0[jc * 4 + 1], 0.f);
        h.z = (_Float16)fmaxf(acc0[jc * 4 + 2], 0.f);
        h.w = (_Float16)fmaxf(acc0[jc * 4 + 3], 0.f);
        *(half4v*)(o0 + jc * 4) = h;
    }
    if (two) {
        _Float16* o1 = o0 + D;
#pragma unroll
        for (int jc = 0; jc < 12; ++jc) {
            half4v h;
            h.x = (_Float16)fmaxf(acc1[jc * 4 + 0], 0.f);
            h.y = (_Float16)fmaxf(acc1[jc * 4 + 1], 0.f);
            h.z = (_Float16)fmaxf(acc1[jc * 4 + 2], 0.f);
            h.w = (_Float16)fmaxf(acc1[jc * 4 + 3], 0.f);
            *(half4v*)(o1 + jc * 4) = h;
        }
    }
}

// ---------------- BN stats + finalize (fused, last-block-done) ----------------

__global__ __launch_bounds__(256) void k_bnstat(const _Float16* __restrict__ tbuf, float* __restrict__ bnstats,
                                                const float* __restrict__ gamma, const float* __restrict__ beta,
                                                float* __restrict__ ss, int* __restrict__ done,
                                                float Ninv, int N) {
    __shared__ float red[2 * D];
    __shared__ int isLast;
    if (threadIdx.x < 2 * D) red[threadIdx.x] = 0.f;
    __syncthreads();
    int tid = blockIdx.x * 256 + threadIdx.x;
    int q = tid % 12;
    int n0 = tid / 12;
    int stride = (gridDim.x * 256) / 12;
    float s0 = 0, s1 = 0, s2 = 0, s3 = 0, q0 = 0, q1 = 0, q2 = 0, q3 = 0;
    for (int n = n0; n < N; n += stride) {
        half4v h = *(const half4v*)(tbuf + (size_t)n * D + q * 4);
        float f0 = (float)h.x, f1 = (float)h.y, f2 = (float)h.z, f3 = (float)h.w;
        s0 += f0; s1 += f1; s2 += f2; s3 += f3;
        q0 += f0 * f0; q1 += f1 * f1; q2 += f2 * f2; q3 += f3 * f3;
    }
    atomicAdd(&red[q * 4 + 0], s0); atomicAdd(&red[q * 4 + 1], s1);
    atomicAdd(&red[q * 4 + 2], s2); atomicAdd(&red[q * 4 + 3], s3);
    atomicAdd(&red[D + q * 4 + 0], q0); atomicAdd(&red[D + q * 4 + 1], q1);
    atomicAdd(&red[D + q * 4 + 2], q2); atomicAdd(&red[D + q * 4 + 3], q3);
    __syncthreads();
    if (threadIdx.x < 2 * D) atomicAdd(&bnstats[threadIdx.x], red[threadIdx.x]);
    __threadfence();
    if (threadIdx.x == 0) {
        int old = atomicAdd(done, 1);
        isLast = (old == (int)gridDim.x - 1);
    }
    __syncthreads();
    if (isLast) {
        __threadfence();
        if (threadIdx.x < D) {
            volatile float* vb = bnstats;
            int t = threadIdx.x;
            float mean = vb[t] * Ninv;
            float var = vb[D + t] * Ninv - mean * mean;
            var = fmaxf(var, 0.f);
            float sc = gamma[t] * rsqrtf(var + BN_EPS);
            ss[t] = sc;
            ss[D + t] = beta[t] - mean * sc;
            // reset for the next step's dispatch (kernel boundary orders visibility)
            bnstats[t] = 0.f;
            bnstats[D + t] = 0.f;
            if (t == 0) atomicExch(done, 0);
        }
    }
}

// ---------------- pool ----------------
// out = BN(max/min over neighbors), outs = dinv[i]*out

__global__ __launch_bounds__(256) void k_pool(const _Float16* __restrict__ tbuf, const int* __restrict__ rowptr,
                                              const int* __restrict__ ecol, const float* __restrict__ ss,
                                              const float* __restrict__ dinv, _Float16* __restrict__ outh,
                                              _Float16* __restrict__ outs, int N) {
    int lane = threadIdx.x & 63;
    int i = (blockIdx.x * 256 + threadIdx.x) >> 6;
    if (i >= N) return;
    int q = lane & 7, slot = lane >> 3;
    int qc = q < 6 ? q : 5;
    int s = rowptr[i], e = rowptr[i + 1];
    float mx[8], mn[8];
#pragma unroll
    for (int j = 0; j < 8; ++j) { mx[j] = -3.4e38f; mn[j] = 3.4e38f; }
    int p = s + slot;
    for (; p + 8 < e; p += 16) {
        int ca = ecol[p], cb = ecol[p + 8];
        half8v ha = *(const half8v*)(tbuf + (size_t)ca * D + qc * 8);
        half8v hb = *(const half8v*)(tbuf + (size_t)cb * D + qc * 8);
#pragma unroll
        for (int j = 0; j < 8; ++j) {
            float fa = (float)ha[j], fb = (float)hb[j];
            mx[j] = fmaxf(mx[j], fmaxf(fa, fb));
            mn[j] = fminf(mn[j], fminf(fa, fb));
        }
    }
    if (p < e) {
        int ca = ecol[p];
        half8v ha = *(const half8v*)(tbuf + (size_t)ca * D + qc * 8);
#pragma unroll
        for (int j = 0; j < 8; ++j) {
            float fa = (float)ha[j];
            mx[j] = fmaxf(mx[j], fa);
            mn[j] = fminf(mn[j], fa);
        }
    }
#pragma unroll
    for (int j = 0; j < 8; ++j) {
        mx[j] = fmaxf(mx[j], __shfl_xor(mx[j], 8));
        mx[j] = fmaxf(mx[j], __shfl_xor(mx[j], 16));
        mx[j] = fmaxf(mx[j], __shfl_xor(mx[j], 32));
        mn[j] = fminf(mn[j], __shfl_xor(mn[j], 8));
        mn[j] = fminf(mn[j], __shfl_xor(mn[j], 16));
        mn[j] = fminf(mn[j], __shfl_xor(mn[j], 32));
    }
    if (lane < 6) {
        float di = dinv[i];
        half8v o, os;
        if (s == e) {
#pragma unroll
            for (int j = 0; j < 8; ++j) { o[j] = (_Float16)0.f; os[j] = (_Float16)0.f; }
        } else {
#pragma unroll
            for (int j = 0; j < 8; ++j) {
                float scj = ss[lane * 8 + j];
                float shj = ss[D + lane * 8 + j];
                float v = (scj >= 0.f) ? scj * mx[j] + shj : scj * mn[j] + shj;
                o[j] = (_Float16)v;
                os[j] = (_Float16)(di * v);
            }
        }
        *(half8v*)(outh + (size_t)i * D + lane * 8) = o;
        *(half8v*)(outs + (size_t)i * D + lane * 8) = os;
    }
}

// ---------------- final pooling + MLP ----------------

__global__ __launch_bounds__(256) void k_gpool(const _Float16* __restrict__ outh, const int* __restrict__ batch,
                                               float* __restrict__ g, int N, int chunk) {
    int lane = threadIdx.x & 63;
    int wid = (blockIdx.x * 256 + threadIdx.x) >> 6;
    int start = wid * chunk;
    if (start >= N || lane >= 12) return;
    int end = start + chunk;
    if (end > N) end = N;
    int curb = batch[start];
    float a0 = 0.f, a1 = 0.f, a2 = 0.f, a3 = 0.f;
    for (int i = start; i < end; ++i) {
        int bi = batch[i];
        if (bi != curb) {
            atomicAdd(&g[curb * D + lane * 4 + 0], a0); atomicAdd(&g[curb * D + lane * 4 + 1], a1);
            atomicAdd(&g[curb * D + lane * 4 + 2], a2); atomicAdd(&g[curb * D + lane * 4 + 3], a3);
            curb = bi; a0 = a1 = a2 = a3 = 0.f;
        }
        half4v h = *(const half4v*)(outh + (size_t)i * D + lane * 4);
        a0 += (float)h.x; a1 += (float)h.y; a2 += (float)h.z; a3 += (float)h.w;
    }
    atomicAdd(&g[curb * D + lane * 4 + 0], a0); atomicAdd(&g[curb * D + lane * 4 + 1], a1);
    atomicAdd(&g[curb * D + lane * 4 + 2], a2); atomicAdd(&g[curb * D + lane * 4 + 3], a3);
}

__global__ __launch_bounds__(256) void k_mlp(const float* __restrict__ g, const float* __restrict__ W1,
                                             const float* __restrict__ b1, const float* __restrict__ W2,
                                             const float* __restrict__ b2, float* __restrict__ out) {
    __shared__ float gL[GNUM * D];
    __shared__ float hL[GNUM * HDIM];
    __shared__ float W1L[D * HDIM];
    int t = threadIdx.x;
    for (int i = t; i < GNUM * D; i += 256) gL[i] = g[i];
    for (int i = t; i < D * HDIM; i += 256) W1L[i] = W1[i];
    __syncthreads();
    for (int i = t; i < GNUM * HDIM; i += 256) {
        int gi = i >> 7, hj = i & 127;
        float a = b1[hj];
        for (int k = 0; k < D; ++k) a += gL[gi * D + k] * W1L[k * HDIM + hj];
        hL[i] = fmaxf(a, 0.f);
    }
    __syncthreads();
    for (int i = t; i < GNUM * ODIM; i += 256) {
        int gi = i / ODIM, oj = i % ODIM;
        float a = b2[oj];
        for (int k = 0; k < HDIM; ++k) a += hL[gi * HDIM + k] * W2[k * ODIM + oj];
        out[i] = a;
    }
}

// ---------------- launch ----------------

extern "C" void kernel_launch(void* const* d_in, const int* in_sizes, int n_in,
                              void* d_out, int out_size, void* d_ws, size_t ws_size,
                              hipStream_t stream) {
    const float* x     = (const float*)d_in[0];
    const int*   ei    = (const int*)d_in[1];
    const int*   batch = (const int*)d_in[2];
    const float* W     = (const float*)d_in[4];
    const float* b     = (const float*)d_in[5];
    const float* gamma = (const float*)d_in[6];
    const float* beta  = (const float*)d_in[7];
    const float* W1    = (const float*)d_in[8];
    const float* b1    = (const float*)d_in[9];
    const float* W2    = (const float*)d_in[10];
    const float* b2    = (const float*)d_in[11];

    int N = in_sizes[0] / D;
    int E = in_sizes[1] / 2;
    const int* row = ei;
    const int* col = ei + E;

    int NBUCK = (N + 255) >> 8;
    int CAP = E / NBUCK + 2048;

    char* w = (char*)d_ws;
    auto alloc = [&](size_t bytes) { char* p = w; w += (bytes + 255) & ~(size_t)255; return p; };
    int*       deg     = (int*)alloc((size_t)N * 4);
    float*     dinv    = (float*)alloc((size_t)N * 4);
    int*       incl    = (int*)alloc((size_t)N * 4);
    int*       bsum    = (int*)alloc(4096);
    int*       rowptr  = (int*)alloc((size_t)(N + 1) * 4);
    int*       ecol    = (int*)alloc((size_t)E * 4);
    int*       btail   = (int*)alloc((size_t)NBUCK * 4);
    int2*      bstore  = (int2*)alloc((size_t)NBUCK * CAP * 8);
    _Float16*  xh      = (_Float16*)alloc((size_t)N * D * 2 + 64);
    _Float16*  xs      = (_Float16*)alloc((size_t)N * D * 2 + 64);
    _Float16*  tx1h    = (_Float16*)alloc((size_t)N * D * 2 + 64);
    _Float16*  tx1s    = (_Float16*)alloc((size_t)N * D * 2 + 64);
    _Float16*  tx2h    = (_Float16*)alloc((size_t)N * D * 2 + 64);
    _Float16*  tbufh   = (_Float16*)alloc((size_t)N * D * 2 + 64);
    _Float16*  outh    = (_Float16*)alloc((size_t)N * D * 2 + 64);
    _Float16*  outs    = (_Float16*)alloc((size_t)N * D * 2 + 64);
    float*     bnstats = (float*)alloc(2 * D * 4);
    float*     ss      = (float*)alloc(2 * D * 4);
    int*       done    = (int*)alloc(256);
    float*     g       = (float*)alloc((size_t)GNUM * D * 4);

    hipMemsetAsync(deg, 0, (size_t)N * 4, stream);
    hipMemsetAsync(btail, 0, (size_t)NBUCK * 4, stream);
    hipMemsetAsync(bnstats, 0, 2 * D * 4, stream);
    hipMemsetAsync(done, 0, 256, stream);
    hipMemsetAsync(g, 0, (size_t)GNUM * D * 4, stream);

    int nbE = (E + 255) / 256;
    int nbN = (N + 255) / 256;

    k_deg<<<nbE, 256, 0, stream>>>(row, deg, E);
    k_scan1<<<nbN, 256, 0, stream>>>(deg, incl, bsum, N);
    k_scan2<<<1, 512, 0, stream>>>(bsum, nbN);
    k_scan3<<<nbN, 256, 0, stream>>>(incl, bsum, rowptr, N);
    k_bucket<<<nbE, 256, 0, stream>>>(row, col, btail, bstore, E, CAP);
    k_fill2<<<NBUCK, 256, 0, stream>>>(bstore, btail, rowptr, ecol, CAP);
    int n4 = N * D / 4;
    k_cvt<<<(n4 + 255) / 256, 256, 0, stream>>>(x, deg, xh, xs, dinv, n4);

    int nbWave = (N * 64 + 255) / 256;
    int nbDense = (((N + 1) / 2) + 255) / 256;
    const _Float16* curh = xh;
    const _Float16* curs = xs;
    for (int step = 0; step < 5; ++step) {
        k_lhat<<<nbWave, 256, 0, stream>>>(curs, rowptr, ecol, dinv, tx1h, tx1s, N);
        k_gather2<<<nbWave, 256, 0, stream>>>(curh, tx1s, rowptr, ecol, dinv, tx2h, N);
        k_dense<<<nbDense, 256, 0, stream>>>(curh, tx1h, tx2h, W, b, tbufh, N);
        k_bnstat<<<120, 256, 0, stream>>>(tbufh, bnstats, gamma, beta, ss, done, 1.f / (float)N, N);
        k_pool<<<nbWave, 256, 0, stream>>>(tbufh, rowptr, ecol, ss, dinv, outh, outs, N);
        curh = outh;
        curs = outs;
    }

    int chunk = 32;
    int nwaves = (N + chunk - 1) / chunk;
    int nbG = (nwaves * 64 + 255) / 256;
    k_gpool<<<nbG, 256, 0, stream>>>(outh, batch, g, N, chunk);
    k_mlp<<<1, 256, 0, stream>>>(g, W1, b1, W2, b2, (float*)d_out);
}

// Round 8
// 1292.106 us; speedup vs baseline: 1.3879x; 1.3879x over previous
//
#include <hip/hip_runtime.h>
#include <hip/hip_bf16.h>

#define D 48
#define GNUM 64
#define HDIM 128
#define ODIM 12
#define BN_EPS 1e-5f

typedef _Float16 half2v __attribute__((ext_vector_type(2)));
typedef _Float16 half4v __attribute__((ext_vector_type(4)));
typedef _Float16 half8v __attribute__((ext_vector_type(8)));

#if __has_builtin(__builtin_amdgcn_fdot2)
#define FDOT2(a, b, c) __builtin_amdgcn_fdot2((a), (b), (c), false)
#else
#define FDOT2(a, b, c) ((c) + (float)(a)[0] * (float)(b)[0] + (float)(a)[1] * (float)(b)[1])
#endif

// ---------------- setup kernels ----------------

__global__ __launch_bounds__(256) void k_deg(const int* __restrict__ row, int* __restrict__ deg, int E) {
    int e = blockIdx.x * 256 + threadIdx.x;
    if (e < E) atomicAdd(&deg[row[e]], 1);
}

__global__ __launch_bounds__(256) void k_scan1(const int* __restrict__ deg, int* __restrict__ incl,
                                               int* __restrict__ bsum, int N) {
    __shared__ int s[256];
    int i = blockIdx.x * 256 + threadIdx.x;
    s[threadIdx.x] = (i < N) ? deg[i] : 0;
    __syncthreads();
    for (int off = 1; off < 256; off <<= 1) {
        int t = (threadIdx.x >= off) ? s[threadIdx.x - off] : 0;
        __syncthreads();
        s[threadIdx.x] += t;
        __syncthreads();
    }
    if (i < N) incl[i] = s[threadIdx.x];
    if (threadIdx.x == 255) bsum[blockIdx.x] = s[255];
}

__global__ __launch_bounds__(512) void k_scan2(int* __restrict__ bsum, int nb) {
    __shared__ int s[512];
    int t = threadIdx.x;
    s[t] = (t < nb) ? bsum[t] : 0;
    __syncthreads();
    for (int off = 1; off < 512; off <<= 1) {
        int v = (t >= off) ? s[t - off] : 0;
        __syncthreads();
        s[t] += v;
        __syncthreads();
    }
    if (t < nb) bsum[t] = s[t];
}

__global__ __launch_bounds__(256) void k_scan3(const int* __restrict__ incl, const int* __restrict__ bsum,
                                               int* __restrict__ rowptr, int N) {
    int i = blockIdx.x * 256 + threadIdx.x;
    if (i < N) {
        int add = (blockIdx.x > 0) ? bsum[blockIdx.x - 1] : 0;
        rowptr[i + 1] = incl[i] + add;
    }
    if (i == 0) rowptr[0] = 0;
}

// Simple CSR fill (accepted cost ~105us: one 64B line eviction per random 4B write).
__global__ __launch_bounds__(256) void k_fill(const int* __restrict__ row, const int* __restrict__ col,
                                              const int* __restrict__ rowptr, int* __restrict__ fillc,
                                              int* __restrict__ ecol, int E) {
    int e = blockIdx.x * 256 + threadIdx.x;
    if (e < E) {
        int r = row[e], c = col[e];
        int p = rowptr[r] + atomicAdd(&fillc[r], 1);
        ecol[p] = c;
    }
}

// xh = fp16(x); xs = fp16(dinv*x); dinv computed inline from deg and stored.
__global__ __launch_bounds__(256) void k_cvt(const float* __restrict__ x, const int* __restrict__ deg,
                                             _Float16* __restrict__ xh, _Float16* __restrict__ xs,
                                             float* __restrict__ dinv, int n4) {
    int i = blockIdx.x * 256 + threadIdx.x;
    if (i < n4) {
        int node = i / 12;  // D/4 chunks per node
        int dg = deg[node];
        float dv = dg > 0 ? rsqrtf((float)dg) : 0.f;
        if (i % 12 == 0) dinv[node] = dv;
        float4 v = ((const float4*)x)[i];
        half4v h, hs;
        h.x = (_Float16)v.x; h.y = (_Float16)v.y; h.z = (_Float16)v.z; h.w = (_Float16)v.w;
        hs.x = (_Float16)(dv * v.x); hs.y = (_Float16)(dv * v.y);
        hs.z = (_Float16)(dv * v.z); hs.w = (_Float16)(dv * v.w);
        ((half4v*)xh)[i] = h;
        ((half4v*)xs)[i] = hs;
    }
}

// ---------------- gather kernels ----------------
// wave per node; 8 slots x 8 lanes; q<6 active (6 x 16B = 96B row); unroll x2.

// tx1 = -dinv[i] * sum(curs[c]); tx1s = dinv[i] * tx1
__global__ __launch_bounds__(256) void k_lhat(const _Float16* __restrict__ curs, const int* __restrict__ rowptr,
                                              const int* __restrict__ ecol, const float* __restrict__ dinv,
                                              _Float16* __restrict__ tx1, _Float16* __restrict__ tx1s, int N) {
    int lane = threadIdx.x & 63;
    int i = (blockIdx.x * 256 + threadIdx.x) >> 6;
    if (i >= N) return;
    int q = lane & 7, slot = lane >> 3;
    int qc = q < 6 ? q : 5;
    int s = rowptr[i], e = rowptr[i + 1];
    float a[8] = {0.f, 0.f, 0.f, 0.f, 0.f, 0.f, 0.f, 0.f};
    int p = s + slot;
    for (; p + 8 < e; p += 16) {
        int ca = ecol[p], cb = ecol[p + 8];
        half8v ha = *(const half8v*)(curs + (size_t)ca * D + qc * 8);
        half8v hb = *(const half8v*)(curs + (size_t)cb * D + qc * 8);
#pragma unroll
        for (int j = 0; j < 8; ++j) a[j] += (float)ha[j] + (float)hb[j];
    }
    if (p < e) {
        int ca = ecol[p];
        half8v ha = *(const half8v*)(curs + (size_t)ca * D + qc * 8);
#pragma unroll
        for (int j = 0; j < 8; ++j) a[j] += (float)ha[j];
    }
#pragma unroll
    for (int j = 0; j < 8; ++j) {
        a[j] += __shfl_xor(a[j], 8);
        a[j] += __shfl_xor(a[j], 16);
        a[j] += __shfl_xor(a[j], 32);
    }
    if (lane < 6) {
        float di = dinv[i];
        half8v o, os;
#pragma unroll
        for (int j = 0; j < 8; ++j) {
            float t = -di * a[j];
            o[j] = (_Float16)t;
            os[j] = (_Float16)(di * t);
        }
        *(half8v*)(tx1 + (size_t)i * D + lane * 8) = o;
        *(half8v*)(tx1s + (size_t)i * D + lane * 8) = os;
    }
}

// tx2 = -2*dinv[i] * sum(tx1s[c]) - tx0
__global__ __launch_bounds__(256) void k_gather2(const _Float16* __restrict__ tx0, const _Float16* __restrict__ tx1s,
                                                 const int* __restrict__ rowptr, const int* __restrict__ ecol,
                                                 const float* __restrict__ dinv, _Float16* __restrict__ tx2, int N) {
    int lane = threadIdx.x & 63;
    int i = (blockIdx.x * 256 + threadIdx.x) >> 6;
    if (i >= N) return;
    int q = lane & 7, slot = lane >> 3;
    int qc = q < 6 ? q : 5;
    int s = rowptr[i], e = rowptr[i + 1];
    float a[8] = {0.f, 0.f, 0.f, 0.f, 0.f, 0.f, 0.f, 0.f};
    int p = s + slot;
    for (; p + 8 < e; p += 16) {
        int ca = ecol[p], cb = ecol[p + 8];
        half8v ha = *(const half8v*)(tx1s + (size_t)ca * D + qc * 8);
        half8v hb = *(const half8v*)(tx1s + (size_t)cb * D + qc * 8);
#pragma unroll
        for (int j = 0; j < 8; ++j) a[j] += (float)ha[j] + (float)hb[j];
    }
    if (p < e) {
        int ca = ecol[p];
        half8v ha = *(const half8v*)(tx1s + (size_t)ca * D + qc * 8);
#pragma unroll
        for (int j = 0; j < 8; ++j) a[j] += (float)ha[j];
    }
#pragma unroll
    for (int j = 0; j < 8; ++j) {
        a[j] += __shfl_xor(a[j], 8);
        a[j] += __shfl_xor(a[j], 16);
        a[j] += __shfl_xor(a[j], 32);
    }
    if (lane < 6) {
        float sc = -2.f * dinv[i];
        half8v h0 = *(const half8v*)(tx0 + (size_t)i * D + lane * 8);
        half8v o;
#pragma unroll
        for (int j = 0; j < 8; ++j) o[j] = (_Float16)(sc * a[j] - (float)h0[j]);
        *(half8v*)(tx2 + (size_t)i * D + lane * 8) = o;
    }
}

// ---------------- dense: t = relu([tx0|tx1|tx2] @ W + b) ----------------

__global__ __launch_bounds__(256) void k_dense(const _Float16* __restrict__ tx0, const _Float16* __restrict__ tx1,
                                               const _Float16* __restrict__ tx2, const float* __restrict__ W,
                                               const float* __restrict__ b, _Float16* __restrict__ tbuf, int N) {
    __shared__ half2v WH2[72 * D];  // [kp][j] = (W[2kp][j], W[2kp+1][j]); 13824 B
    __shared__ float bL[D];
    for (int t = threadIdx.x; t < 72 * D; t += 256) {
        int kp = t / D, j = t % D;
        half2v w;
        w.x = (_Float16)W[(2 * kp) * D + j];
        w.y = (_Float16)W[(2 * kp + 1) * D + j];
        WH2[t] = w;
    }
    if (threadIdx.x < D) bL[threadIdx.x] = b[threadIdx.x];
    __syncthreads();

    int base = (blockIdx.x * 256 + threadIdx.x) * 2;
    if (base >= N) return;
    bool two = (base + 1) < N;

    const _Float16* rowsA[3] = {tx0 + (size_t)base * D, tx1 + (size_t)base * D, tx2 + (size_t)base * D};
    size_t off2 = two ? D : 0;

    float acc0[D], acc1[D];
#pragma unroll
    for (int j = 0; j < D; ++j) { acc0[j] = bL[j]; acc1[j] = bL[j]; }

    for (int s = 0; s < 3; ++s) {
        const half2v* xa = (const half2v*)rowsA[s];
        const half2v* xb = (const half2v*)(rowsA[s] + off2);
#pragma unroll 4
        for (int g = 0; g < 24; ++g) {
            half2v va = xa[g], vb = xb[g];
            int kp = s * 24 + g;
            const half8v* wr = (const half8v*)&WH2[kp * D];
#pragma unroll
            for (int jc = 0; jc < 12; ++jc) {
                half8v w = wr[jc];
                half2v w0; w0.x = w[0]; w0.y = w[1];
                half2v w1; w1.x = w[2]; w1.y = w[3];
                half2v w2; w2.x = w[4]; w2.y = w[5];
                half2v w3; w3.x = w[6]; w3.y = w[7];
                acc0[jc * 4 + 0] = FDOT2(va, w0, acc0[jc * 4 + 0]);
                acc0[jc * 4 + 1] = FDOT2(va, w1, acc0[jc * 4 + 1]);
                acc0[jc * 4 + 2] = FDOT2(va, w2, acc0[jc * 4 + 2]);
                acc0[jc * 4 + 3] = FDOT2(va, w3, acc0[jc * 4 + 3]);
                acc1[jc * 4 + 0] = FDOT2(vb, w0, acc1[jc * 4 + 0]);
                acc1[jc * 4 + 1] = FDOT2(vb, w1, acc1[jc * 4 + 1]);
                acc1[jc * 4 + 2] = FDOT2(vb, w2, acc1[jc * 4 + 2]);
                acc1[jc * 4 + 3] = FDOT2(vb, w3, acc1[jc * 4 + 3]);
            }
        }
    }

    _Float16* o0 = tbuf + (size_t)base * D;
#pragma unroll
    for (int jc = 0; jc < 12; ++jc) {
        half4v h;
        h.x = (_Float16)fmaxf(acc0[jc * 4 + 0], 0.f);
        h.y = (_Float16)fmaxf(acc0[jc * 4 + 1], 0.f);
        h.z = (_Float16)fmaxf(acc0[jc * 4 + 2], 0.f);
        h.w = (_Float16)fmaxf(acc0[jc * 4 + 3], 0.f);
        *(half4v*)(o0 + jc * 4) = h;
    }
    if (two) {
        _Float16* o1 = o0 + D;
#pragma unroll
        for (int jc = 0; jc < 12; ++jc) {
            half4v h;
            h.x = (_Float16)fmaxf(acc1[jc * 4 + 0], 0.f);
            h.y = (_Float16)fmaxf(acc1[jc * 4 + 1], 0.f);
            h.z = (_Float16)fmaxf(acc1[jc * 4 + 2], 0.f);
            h.w = (_Float16)fmaxf(acc1[jc * 4 + 3], 0.f);
            *(half4v*)(o1 + jc * 4) = h;
        }
    }
}

// ---------------- BN stats + finalize (fused, last-block-done) ----------------

__global__ __launch_bounds__(256) void k_bnstat(const _Float16* __restrict__ tbuf, float* __restrict__ bnstats,
                                                const float* __restrict__ gamma, const float* __restrict__ beta,
                                                float* __restrict__ ss, int* __restrict__ done,
                                                float Ninv, int N) {
    __shared__ float red[2 * D];
    __shared__ int isLast;
    if (threadIdx.x < 2 * D) red[threadIdx.x] = 0.f;
    __syncthreads();
    int tid = blockIdx.x * 256 + threadIdx.x;
    int q = tid % 12;
    int n0 = tid / 12;
    int stride = (gridDim.x * 256) / 12;
    float s0 = 0, s1 = 0, s2 = 0, s3 = 0, q0 = 0, q1 = 0, q2 = 0, q3 = 0;
    for (int n = n0; n < N; n += stride) {
        half4v h = *(const half4v*)(tbuf + (size_t)n * D + q * 4);
        float f0 = (float)h.x, f1 = (float)h.y, f2 = (float)h.z, f3 = (float)h.w;
        s0 += f0; s1 += f1; s2 += f2; s3 += f3;
        q0 += f0 * f0; q1 += f1 * f1; q2 += f2 * f2; q3 += f3 * f3;
    }
    atomicAdd(&red[q * 4 + 0], s0); atomicAdd(&red[q * 4 + 1], s1);
    atomicAdd(&red[q * 4 + 2], s2); atomicAdd(&red[q * 4 + 3], s3);
    atomicAdd(&red[D + q * 4 + 0], q0); atomicAdd(&red[D + q * 4 + 1], q1);
    atomicAdd(&red[D + q * 4 + 2], q2); atomicAdd(&red[D + q * 4 + 3], q3);
    __syncthreads();
    if (threadIdx.x < 2 * D) atomicAdd(&bnstats[threadIdx.x], red[threadIdx.x]);
    __threadfence();
    if (threadIdx.x == 0) {
        int old = atomicAdd(done, 1);
        isLast = (old == (int)gridDim.x - 1);
    }
    __syncthreads();
    if (isLast) {
        __threadfence();
        if (threadIdx.x < D) {
            volatile float* vb = bnstats;
            int t = threadIdx.x;
            float mean = vb[t] * Ninv;
            float var = vb[D + t] * Ninv - mean * mean;
            var = fmaxf(var, 0.f);
            float sc = gamma[t] * rsqrtf(var + BN_EPS);
            ss[t] = sc;
            ss[D + t] = beta[t] - mean * sc;
            bnstats[t] = 0.f;
            bnstats[D + t] = 0.f;
            if (t == 0) atomicExch(done, 0);
        }
    }
}

// ---------------- pool ----------------
// out = BN(max/min over neighbors), outs = dinv[i]*out

__global__ __launch_bounds__(256) void k_pool(const _Float16* __restrict__ tbuf, const int* __restrict__ rowptr,
                                              const int* __restrict__ ecol, const float* __restrict__ ss,
                                              const float* __restrict__ dinv, _Float16* __restrict__ outh,
                                              _Float16* __restrict__ outs, int N) {
    int lane = threadIdx.x & 63;
    int i = (blockIdx.x * 256 + threadIdx.x) >> 6;
    if (i >= N) return;
    int q = lane & 7, slot = lane >> 3;
    int qc = q < 6 ? q : 5;
    int s = rowptr[i], e = rowptr[i + 1];
    float mx[8], mn[8];
#pragma unroll
    for (int j = 0; j < 8; ++j) { mx[j] = -3.4e38f; mn[j] = 3.4e38f; }
    int p = s + slot;
    for (; p + 8 < e; p += 16) {
        int ca = ecol[p], cb = ecol[p + 8];
        half8v ha = *(const half8v*)(tbuf + (size_t)ca * D + qc * 8);
        half8v hb = *(const half8v*)(tbuf + (size_t)cb * D + qc * 8);
#pragma unroll
        for (int j = 0; j < 8; ++j) {
            float fa = (float)ha[j], fb = (float)hb[j];
            mx[j] = fmaxf(mx[j], fmaxf(fa, fb));
            mn[j] = fminf(mn[j], fminf(fa, fb));
        }
    }
    if (p < e) {
        int ca = ecol[p];
        half8v ha = *(const half8v*)(tbuf + (size_t)ca * D + qc * 8);
#pragma unroll
        for (int j = 0; j < 8; ++j) {
            float fa = (float)ha[j];
            mx[j] = fmaxf(mx[j], fa);
            mn[j] = fminf(mn[j], fa);
        }
    }
#pragma unroll
    for (int j = 0; j < 8; ++j) {
        mx[j] = fmaxf(mx[j], __shfl_xor(mx[j], 8));
        mx[j] = fmaxf(mx[j], __shfl_xor(mx[j], 16));
        mx[j] = fmaxf(mx[j], __shfl_xor(mx[j], 32));
        mn[j] = fminf(mn[j], __shfl_xor(mn[j], 8));
        mn[j] = fminf(mn[j], __shfl_xor(mn[j], 16));
        mn[j] = fminf(mn[j], __shfl_xor(mn[j], 32));
    }
    if (lane < 6) {
        float di = dinv[i];
        half8v o, os;
        if (s == e) {
#pragma unroll
            for (int j = 0; j < 8; ++j) { o[j] = (_Float16)0.f; os[j] = (_Float16)0.f; }
        } else {
#pragma unroll
            for (int j = 0; j < 8; ++j) {
                float scj = ss[lane * 8 + j];
                float shj = ss[D + lane * 8 + j];
                float v = (scj >= 0.f) ? scj * mx[j] + shj : scj * mn[j] + shj;
                o[j] = (_Float16)v;
                os[j] = (_Float16)(di * v);
            }
        }
        *(half8v*)(outh + (size_t)i * D + lane * 8) = o;
        *(half8v*)(outs + (size_t)i * D + lane * 8) = os;
    }
}

// ---------------- final pooling + MLP ----------------

__global__ __launch_bounds__(256) void k_gpool(const _Float16* __restrict__ outh, const int* __restrict__ batch,
                                               float* __restrict__ g, int N, int chunk) {
    int lane = threadIdx.x & 63;
    int wid = (blockIdx.x * 256 + threadIdx.x) >> 6;
    int start = wid * chunk;
    if (start >= N || lane >= 12) return;
    int end = start + chunk;
    if (end > N) end = N;
    int curb = batch[start];
    float a0 = 0.f, a1 = 0.f, a2 = 0.f, a3 = 0.f;
    for (int i = start; i < end; ++i) {
        int bi = batch[i];
        if (bi != curb) {
            atomicAdd(&g[curb * D + lane * 4 + 0], a0); atomicAdd(&g[curb * D + lane * 4 + 1], a1);
            atomicAdd(&g[curb * D + lane * 4 + 2], a2); atomicAdd(&g[curb * D + lane * 4 + 3], a3);
            curb = bi; a0 = a1 = a2 = a3 = 0.f;
        }
        half4v h = *(const half4v*)(outh + (size_t)i * D + lane * 4);
        a0 += (float)h.x; a1 += (float)h.y; a2 += (float)h.z; a3 += (float)h.w;
    }
    atomicAdd(&g[curb * D + lane * 4 + 0], a0); atomicAdd(&g[curb * D + lane * 4 + 1], a1);
    atomicAdd(&g[curb * D + lane * 4 + 2], a2); atomicAdd(&g[curb * D + lane * 4 + 3], a3);
}

__global__ __launch_bounds__(256) void k_mlp(const float* __restrict__ g, const float* __restrict__ W1,
                                             const float* __restrict__ b1, const float* __restrict__ W2,
                                             const float* __restrict__ b2, float* __restrict__ out) {
    __shared__ float gL[GNUM * D];
    __shared__ float hL[GNUM * HDIM];
    __shared__ float W1L[D * HDIM];
    int t = threadIdx.x;
    for (int i = t; i < GNUM * D; i += 256) gL[i] = g[i];
    for (int i = t; i < D * HDIM; i += 256) W1L[i] = W1[i];
    __syncthreads();
    for (int i = t; i < GNUM * HDIM; i += 256) {
        int gi = i >> 7, hj = i & 127;
        float a = b1[hj];
        for (int k = 0; k < D; ++k) a += gL[gi * D + k] * W1L[k * HDIM + hj];
        hL[i] = fmaxf(a, 0.f);
    }
    __syncthreads();
    for (int i = t; i < GNUM * ODIM; i += 256) {
        int gi = i / ODIM, oj = i % ODIM;
        float a = b2[oj];
        for (int k = 0; k < HDIM; ++k) a += hL[gi * HDIM + k] * W2[k * ODIM + oj];
        out[i] = a;
    }
}

// ---------------- launch ----------------

extern "C" void kernel_launch(void* const* d_in, const int* in_sizes, int n_in,
                              void* d_out, int out_size, void* d_ws, size_t ws_size,
                              hipStream_t stream) {
    const float* x     = (const float*)d_in[0];
    const int*   ei    = (const int*)d_in[1];
    const int*   batch = (const int*)d_in[2];
    const float* W     = (const float*)d_in[4];
    const float* b     = (const float*)d_in[5];
    const float* gamma = (const float*)d_in[6];
    const float* beta  = (const float*)d_in[7];
    const float* W1    = (const float*)d_in[8];
    const float* b1    = (const float*)d_in[9];
    const float* W2    = (const float*)d_in[10];
    const float* b2    = (const float*)d_in[11];

    int N = in_sizes[0] / D;
    int E = in_sizes[1] / 2;
    const int* row = ei;
    const int* col = ei + E;

    char* w = (char*)d_ws;
    auto alloc = [&](size_t bytes) { char* p = w; w += (bytes + 255) & ~(size_t)255; return p; };
    int*       deg     = (int*)alloc((size_t)N * 4);
    float*     dinv    = (float*)alloc((size_t)N * 4);
    int*       fillc   = (int*)alloc((size_t)N * 4);
    int*       incl    = (int*)alloc((size_t)N * 4);
    int*       bsum    = (int*)alloc(4096);
    int*       rowptr  = (int*)alloc((size_t)(N + 1) * 4);
    int*       ecol    = (int*)alloc((size_t)E * 4);
    _Float16*  xh      = (_Float16*)alloc((size_t)N * D * 2 + 64);
    _Float16*  xs      = (_Float16*)alloc((size_t)N * D * 2 + 64);
    _Float16*  tx1h    = (_Float16*)alloc((size_t)N * D * 2 + 64);
    _Float16*  tx1s    = (_Float16*)alloc((size_t)N * D * 2 + 64);
    _Float16*  tx2h    = (_Float16*)alloc((size_t)N * D * 2 + 64);
    _Float16*  tbufh   = (_Float16*)alloc((size_t)N * D * 2 + 64);
    _Float16*  outh    = (_Float16*)alloc((size_t)N * D * 2 + 64);
    _Float16*  outs    = (_Float16*)alloc((size_t)N * D * 2 + 64);
    float*     bnstats = (float*)alloc(2 * D * 4);
    float*     ss      = (float*)alloc(2 * D * 4);
    int*       done    = (int*)alloc(256);
    float*     g       = (float*)alloc((size_t)GNUM * D * 4);

    hipMemsetAsync(deg, 0, (size_t)N * 4, stream);
    hipMemsetAsync(fillc, 0, (size_t)N * 4, stream);
    hipMemsetAsync(bnstats, 0, 2 * D * 4, stream);
    hipMemsetAsync(done, 0, 256, stream);
    hipMemsetAsync(g, 0, (size_t)GNUM * D * 4, stream);

    int nbE = (E + 255) / 256;
    int nbN = (N + 255) / 256;

    k_deg<<<nbE, 256, 0, stream>>>(row, deg, E);
    k_scan1<<<nbN, 256, 0, stream>>>(deg, incl, bsum, N);
    k_scan2<<<1, 512, 0, stream>>>(bsum, nbN);
    k_scan3<<<nbN, 256, 0, stream>>>(incl, bsum, rowptr, N);
    k_fill<<<nbE, 256, 0, stream>>>(row, col, rowptr, fillc, ecol, E);
    int n4 = N * D / 4;
    k_cvt<<<(n4 + 255) / 256, 256, 0, stream>>>(x, deg, xh, xs, dinv, n4);

    int nbWave = (N * 64 + 255) / 256;
    int nbDense = (((N + 1) / 2) + 255) / 256;
    const _Float16* curh = xh;
    const _Float16* curs = xs;
    for (int step = 0; step < 5; ++step) {
        k_lhat<<<nbWave, 256, 0, stream>>>(curs, rowptr, ecol, dinv, tx1h, tx1s, N);
        k_gather2<<<nbWave, 256, 0, stream>>>(curh, tx1s, rowptr, ecol, dinv, tx2h, N);
        k_dense<<<nbDense, 256, 0, stream>>>(curh, tx1h, tx2h, W, b, tbufh, N);
        k_bnstat<<<120, 256, 0, stream>>>(tbufh, bnstats, gamma, beta, ss, done, 1.f / (float)N, N);
        k_pool<<<nbWave, 256, 0, stream>>>(tbufh, rowptr, ecol, ss, dinv, outh, outs, N);
        curh = outh;
        curs = outs;
    }

    int chunk = 32;
    int nwaves = (N + chunk - 1) / chunk;
    int nbG = (nwaves * 64 + 255) / 256;
    k_gpool<<<nbG, 256, 0, stream>>>(outh, batch, g, N, chunk);
    k_mlp<<<1, 256, 0, stream>>>(g, W1, b1, W2, b2, (float*)d_out);
}